// Round 2
// baseline (226.214 us; speedup 1.0000x reference)
//
#include <hip/hip_runtime.h>

// ---- problem constants (B,H0,W0,C)=(16,56,56,96), NH=3, WS=7, SS=3, HID=384, NCL=128 ----
#define NB 16
#define NHH 56
#define NWW 56
#define NC 96
#define NL (NHH*NWW)          // 3136
#define NTOK (NB*NL)          // 50176
#define WSZ 7
#define NT 49                 // tokens per window
#define SSH 3
#define NWIN 1024             // 16 * 8 * 8
#define HDIM 32
#define HID_ 384
#define NCL_ 128
#define NLIT 768
#define EPS_ 1e-6f
#define LOG_EPS -13.815510558f

typedef unsigned short u16;
typedef unsigned int   u32;
typedef __attribute__((ext_vector_type(8))) short short8;   // 8 bf16 (4 VGPRs)
typedef __attribute__((ext_vector_type(4))) float f32x4;    // MFMA C/D

__device__ __forceinline__ float us2f(u16 u) {
  union { u32 u; float f; } x; x.u = ((u32)u) << 16; return x.f;
}
__device__ __forceinline__ u16 f2us(float f) {   // RNE float->bf16
  union { float f; u32 u; } x; x.f = f;
  u32 lsb = (x.u >> 16) & 1u;
  return (u16)((x.u + 0x7fffu + lsb) >> 16);
}
__device__ __forceinline__ float sigmoidf_(float x) { return 1.f / (1.f + __expf(-x)); }

// ---------------- K0: build bf16 constants ----------------
// maskb is stored COLUMN-INTERLEAVED: permuted col q holds source literal
// j = (q&1) ? 384 + q/2 : q/2.  k4 writes lit[] in the same interleaved
// order (literal o and literal 384+o are adjacent -> one u32 LDS write).
__global__ __launch_bounds__(256) void k0_prep(const float* __restrict__ tm_inc,
                                               const float* __restrict__ pin_w,
                                               const float* __restrict__ tm_out,
                                               const float* __restrict__ qkv_w,
                                               const float* __restrict__ proj_w,
                                               u16* __restrict__ maskb,
                                               u16* __restrict__ pinwb,
                                               u16* __restrict__ tmoT,
                                               u16* __restrict__ qkvwb,
                                               u16* __restrict__ projwb) {
  int idx = blockIdx.x * 256 + threadIdx.x;
  if (idx < NCL_ * NLIT) {
    int c = idx / NLIT, q = idx - c * NLIT;
    int j = (q & 1) ? (q >> 1) + HID_ : (q >> 1);
    maskb[idx] = (tm_inc[(size_t)c * NLIT + j] > 0.f) ? (u16)0x3F80 : (u16)0;
  }
  if (idx < HID_ * NC)
    pinwb[idx] = f2us(pin_w[idx]);
  if (idx < NC * NCL_) {
    int c = idx / NCL_, k = idx - c * NCL_;
    tmoT[idx] = f2us(tm_out[(size_t)k * NC + c]);
  }
  if (idx < 3 * NC * NC)
    qkvwb[idx] = f2us(qkv_w[idx]);
  if (idx < NC * NC)
    projwb[idx] = f2us(proj_w[idx]);
}

// ---------------- K2: LN1 + window gather + MFMA attention + proj + residual scatter ----------------
// One block = one window. 4 waves; wave w owns query rows 16w..16w+15.
// syb triple-duty: LN1'd y -> q (QKV phase, wave-own rows) -> attn-out (PV, wave-own rows).
// NO barrier after LN: wave w's A-frag rows are written by wave w's own LN threads.
// LDS: syb 13,312 + sk 13,312 + svT 13,824 = 40,448 B -> 4 blocks/CU = whole 1024-block grid resident.
// sp (softmax P staging) ALIASES sk, fenced by barrier B3s.
__global__ __launch_bounds__(256, 4) void k2_attn(const float* __restrict__ x,
                                               const float* __restrict__ n1g,
                                               const float* __restrict__ n1b,
                                               const u16* __restrict__ qkvwb,
                                               const float* __restrict__ qkv_b,
                                               const u16* __restrict__ projwb,
                                               const float* __restrict__ proj_b,
                                               float* __restrict__ x1) {
  __shared__ __align__(16) u16 syb[64 * 104];
  __shared__ __align__(16) u16 sk [64 * 104];
  __shared__ __align__(16) u16 svT[96 * 72];
  const int tid  = threadIdx.x;
  const int wave = tid >> 6;
  const int lane = tid & 63;
  const int l16  = lane & 15;
  const int quad = lane >> 4;
  const int win  = blockIdx.x;
  const int t0   = wave * 16;
  const int bb = win >> 6, wl = win & 63;
  const int hbase = (wl >> 3) * WSZ, wbase = (wl & 7) * WSZ;

  // ---- LN1 head: 4 threads per token; gather from x with inverse global roll ----
  {
    const int t = tid >> 2, s = tid & 3;
    if (t < NT) {
      int hp = hbase + t / WSZ, wp = wbase + t % WSZ;
      int h = hp + SSH; if (h >= NHH) h -= NHH;
      int w = wp + SSH; if (w >= NWW) w -= NWW;
      const float* xp = x + ((size_t)bb * NL + (size_t)h * NWW + w) * NC;
      float4 v[6];
      float sum = 0.f;
      #pragma unroll
      for (int k = 0; k < 6; ++k) {
        v[k] = *reinterpret_cast<const float4*>(xp + s * 4 + k * 16);
        sum += v[k].x + v[k].y + v[k].z + v[k].w;
      }
      sum += __shfl_xor(sum, 1); sum += __shfl_xor(sum, 2);
      float mean = sum * (1.f / 96.f);
      float ssq = 0.f;
      #pragma unroll
      for (int k = 0; k < 6; ++k) {
        float d0 = v[k].x - mean, d1 = v[k].y - mean;
        float d2 = v[k].z - mean, d3 = v[k].w - mean;
        ssq += d0 * d0 + d1 * d1 + d2 * d2 + d3 * d3;
      }
      ssq += __shfl_xor(ssq, 1); ssq += __shfl_xor(ssq, 2);
      float rstd = rsqrtf(ssq * (1.f / 96.f) + 1e-5f);
      #pragma unroll
      for (int k = 0; k < 6; ++k) {
        int c = s * 4 + k * 16;
        const float4 g4 = *reinterpret_cast<const float4*>(n1g + c);
        const float4 b4 = *reinterpret_cast<const float4*>(n1b + c);
        syb[t * 104 + c + 0] = f2us((v[k].x - mean) * rstd * g4.x + b4.x);
        syb[t * 104 + c + 1] = f2us((v[k].y - mean) * rstd * g4.y + b4.y);
        syb[t * 104 + c + 2] = f2us((v[k].z - mean) * rstd * g4.z + b4.z);
        syb[t * 104 + c + 3] = f2us((v[k].w - mean) * rstd * g4.w + b4.w);
      }
    } else {
      #pragma unroll
      for (int k = 0; k < 6; ++k) {
        int c = s * 4 + k * 16;
        syb[t * 104 + c + 0] = 0; syb[t * 104 + c + 1] = 0;
        syb[t * 104 + c + 2] = 0; syb[t * 104 + c + 3] = 0;
      }
    }
  }
  // NO __syncthreads() here: A-frag rows below are wave-own (see header comment).

  // ---- QKV: M=64, N=288 (18 tiles), K=96 (3 steps); depth-4 B-frag ring. ----
  {
    short8 afr[3];
    #pragma unroll
    for (int ks = 0; ks < 3; ++ks)
      afr[ks] = *reinterpret_cast<const short8*>(&syb[(t0 + l16) * 104 + quad * 8 + ks * 32]);
    short8 rb[4][3];
    #pragma unroll
    for (int p = 0; p < 4; ++p)
      #pragma unroll
      for (int ks = 0; ks < 3; ++ks)
        rb[p][ks] = *reinterpret_cast<const short8*>(
            qkvwb + (size_t)(p * 16 + l16) * NC + quad * 8 + ks * 32);
    #pragma unroll
    for (int nt = 0; nt < 18; ++nt) {
      const int n0 = nt * 16;
      const float bias = qkv_b[n0 + l16];
      short8 b0 = rb[nt & 3][0], b1 = rb[nt & 3][1], b2 = rb[nt & 3][2];
      if (nt + 4 < 18) {
        #pragma unroll
        for (int ks = 0; ks < 3; ++ks)
          rb[nt & 3][ks] = *reinterpret_cast<const short8*>(
              qkvwb + (size_t)((nt + 4) * 16 + l16) * NC + quad * 8 + ks * 32);
      }
      f32x4 acc = {0.f, 0.f, 0.f, 0.f};
      acc = __builtin_amdgcn_mfma_f32_16x16x32_bf16(afr[0], b0, acc, 0, 0, 0);
      acc = __builtin_amdgcn_mfma_f32_16x16x32_bf16(afr[1], b1, acc, 0, 0, 0);
      acc = __builtin_amdgcn_mfma_f32_16x16x32_bf16(afr[2], b2, acc, 0, 0, 0);
      const int part = nt / 6;                 // 0=q 1=k 2=v
      const int oc = n0 - part * 96 + l16;
      if (part < 2) {
        u16* dst = (part == 0) ? syb : sk;     // q overwrites y in wave-own rows
        #pragma unroll
        for (int r = 0; r < 4; ++r)
          dst[(t0 + quad * 4 + r) * 104 + oc] = f2us(acc[r] + bias);
      } else {
        #pragma unroll
        for (int r = 0; r < 4; ++r)
          svT[oc * 72 + (t0 + quad * 4 + r)] = f2us(acc[r] + bias);
      }
    }
  }
  __syncthreads();   // B2: k/v (cross-wave) must be complete

  // ---- all-head scores first, then per-head softmax+PV ----
  u16* spw = sk + wave * 16 * 72;              // sp ALIASES sk (sk dead after score phase)
  const float sscale = 0.17677669529663687f;
  short8 qf[3];
  f32x4 s[3][4];
  #pragma unroll
  for (int h = 0; h < 3; ++h)
    qf[h] = *reinterpret_cast<const short8*>(&syb[(t0 + l16) * 104 + h * HDIM + quad * 8]);
  #pragma unroll
  for (int h = 0; h < 3; ++h) {
    const int d0 = h * HDIM;
    #pragma unroll
    for (int nt = 0; nt < 4; ++nt) {
      short8 kf = *reinterpret_cast<const short8*>(&sk[(nt * 16 + l16) * 104 + d0 + quad * 8]);
      f32x4 a = {0.f, 0.f, 0.f, 0.f};
      s[h][nt] = __builtin_amdgcn_mfma_f32_16x16x32_bf16(qf[h], kf, a, 0, 0, 0);
    }
  }
  __syncthreads();   // B3s: all sk reads complete before spw (sk-alias) writes
  #pragma unroll
  for (int h = 0; h < 3; ++h) {
    const int d0 = h * HDIM;
    #pragma unroll
    for (int nt = 0; nt < 4; ++nt)
      #pragma unroll
      for (int r = 0; r < 4; ++r) s[h][nt][r] *= sscale;
    if (l16 >= 1) {                       // key col 48+l16 >= 49 -> mask
      #pragma unroll
      for (int r = 0; r < 4; ++r) s[h][3][r] = -1e30f;
    }
    #pragma unroll
    for (int r = 0; r < 4; ++r) {
      float m = fmaxf(fmaxf(s[h][0][r], s[h][1][r]), fmaxf(s[h][2][r], s[h][3][r]));
      #pragma unroll
      for (int off = 8; off > 0; off >>= 1) m = fmaxf(m, __shfl_xor(m, off, 16));
      float e0 = __expf(s[h][0][r] - m), e1 = __expf(s[h][1][r] - m);
      float e2 = __expf(s[h][2][r] - m), e3 = __expf(s[h][3][r] - m);
      float sum = e0 + e1 + e2 + e3;
      #pragma unroll
      for (int off = 8; off > 0; off >>= 1) sum += __shfl_xor(sum, off, 16);
      float inv = 1.f / sum;
      const int row = quad * 4 + r;
      spw[row * 72 +      l16] = f2us(e0 * inv);
      spw[row * 72 + 16 + l16] = f2us(e1 * inv);
      spw[row * 72 + 32 + l16] = f2us(e2 * inv);
      spw[row * 72 + 48 + l16] = f2us(e3 * inv);
    }
    short8 pa[2];
    pa[0] = *reinterpret_cast<const short8*>(&spw[l16 * 72 + quad * 8]);
    pa[1] = *reinterpret_cast<const short8*>(&spw[l16 * 72 + 32 + quad * 8]);
    #pragma unroll
    for (int nt = 0; nt < 2; ++nt) {
      const int c0 = d0 + nt * 16;
      f32x4 acc = {0.f, 0.f, 0.f, 0.f};
      #pragma unroll
      for (int ks = 0; ks < 2; ++ks) {
        short8 vb = *reinterpret_cast<const short8*>(&svT[(c0 + l16) * 72 + ks * 32 + quad * 8]);
        acc = __builtin_amdgcn_mfma_f32_16x16x32_bf16(pa[ks], vb, acc, 0, 0, 0);
      }
      #pragma unroll
      for (int r = 0; r < 4; ++r)
        syb[(t0 + quad * 4 + r) * 104 + c0 + l16] = f2us(acc[r]);
    }
  }

  // ---- proj: N=96 (6 tiles), K=96 (3 steps); prefetched residuals + depth-2 B ring ----
  {
    short8 aa[3];
    #pragma unroll
    for (int ks = 0; ks < 3; ++ks)
      aa[ks] = *reinterpret_cast<const short8*>(&syb[(t0 + l16) * 104 + quad * 8 + ks * 32]);

    size_t tokr[4]; bool tval[4];
    #pragma unroll
    for (int r = 0; r < 4; ++r) {
      const int t = t0 + quad * 4 + r;
      tval[r] = (t < NT);
      int rr = t / WSZ + SSH; if (rr >= WSZ) rr -= WSZ;
      int qq = t % WSZ + SSH; if (qq >= WSZ) qq -= WSZ;
      tokr[r] = (size_t)bb * NL + (size_t)(hbase + rr) * NWW + (wbase + qq);
    }
    float xv[6][4];
    #pragma unroll
    for (int nt = 0; nt < 6; ++nt)
      #pragma unroll
      for (int r = 0; r < 4; ++r)
        xv[nt][r] = tval[r] ? x[tokr[r] * NC + nt * 16 + l16] : 0.f;

    short8 pbr[2][3];
    #pragma unroll
    for (int ks = 0; ks < 3; ++ks)
      pbr[0][ks] = *reinterpret_cast<const short8*>(
          projwb + (size_t)l16 * NC + quad * 8 + ks * 32);
    #pragma unroll
    for (int nt = 0; nt < 6; ++nt) {
      const int n0 = nt * 16;
      const float pb = proj_b[n0 + l16];
      short8 b0 = pbr[nt & 1][0], b1 = pbr[nt & 1][1], b2 = pbr[nt & 1][2];
      if (nt + 1 < 6) {
        #pragma unroll
        for (int ks = 0; ks < 3; ++ks)
          pbr[(nt + 1) & 1][ks] = *reinterpret_cast<const short8*>(
              projwb + (size_t)((nt + 1) * 16 + l16) * NC + quad * 8 + ks * 32);
      }
      f32x4 acc = {0.f, 0.f, 0.f, 0.f};
      acc = __builtin_amdgcn_mfma_f32_16x16x32_bf16(aa[0], b0, acc, 0, 0, 0);
      acc = __builtin_amdgcn_mfma_f32_16x16x32_bf16(aa[1], b1, acc, 0, 0, 0);
      acc = __builtin_amdgcn_mfma_f32_16x16x32_bf16(aa[2], b2, acc, 0, 0, 0);
      #pragma unroll
      for (int r = 0; r < 4; ++r) {
        if (tval[r])
          x1[tokr[r] * NC + n0 + l16] = xv[nt][r] + acc[r] + pb;
      }
    }
  }
}

// ---------------- K4: double-LN + TM-FFN via MFMA; 16 tokens/block, 4 waves (256 thr) ----------------
// Block halved vs prior round: per-lane work is IDENTICAL (24 softplus/lane,
// 48 clause MFMA/wave) but LDS = 16*776*2 = 24,832 B -> 6 blocks/CU (24 waves).
// 6 independent barrier groups (vs 3) double the cross-block overlap that hides
// the VALU/softplus stalls; barriers fence 4 waves instead of 8.
// szb (16x104) and claT (16x136) ALIAS lit (16x776); fenced by B1b / B2b.
// lit columns INTERLEAVED (literal o at col 2o, literal 384+o at 2o+1, matching
// k0's maskb permutation) -> one aligned u32 store per literal pair.
// Clause gemm: wave w owns clause tiles {2w, 2w+1}; both share one A-frag read
// per ks (halves lit ds_read traffic), 2 independent MFMA chains.
__global__ __launch_bounds__(256, 6) void k4_ffn(const float* __restrict__ x1,
                                              const float* __restrict__ g2,
                                              const float* __restrict__ b2,
                                              const float* __restrict__ gf,
                                              const float* __restrict__ bf,
                                              const u16* __restrict__ pinwb,
                                              const float* __restrict__ pin_b,
                                              const u16* __restrict__ maskb,
                                              const u16* __restrict__ tmoT,
                                              const float* __restrict__ gate,
                                              float* __restrict__ out) {
  __shared__ __align__(16) u16 lit[16 * 776];   // bf16 log-literals [t][perm(j)], 24,832 B
  u16* szb  = lit;                              // alias: dies at B1b
  u16* claT = lit;                              // alias: born after B2b
  const int tid  = threadIdx.x;
  const int wave = tid >> 6;
  const int lane = tid & 63;
  const int l16  = lane & 15;
  const int quad = lane >> 4;
  const size_t tok0 = (size_t)blockIdx.x * 16;

  // ---- LN(LN(x1)) head: 16 lanes per token, 6 channels each (float2 x 3) ----
  {
    const int t = tid >> 4, s = tid & 15;      // t in [0,16)
    const float* xp = x1 + (tok0 + t) * NC;
    float2 v[3];
    float sum = 0.f;
    #pragma unroll
    for (int k = 0; k < 3; ++k) {
      const int c = s * 2 + k * 32;
      v[k] = *reinterpret_cast<const float2*>(xp + c);
      sum += v[k].x + v[k].y;
    }
    #pragma unroll
    for (int off = 8; off > 0; off >>= 1) sum += __shfl_xor(sum, off, 16);
    const float mean = sum * (1.f / 96.f);
    float ssq = 0.f;
    #pragma unroll
    for (int k = 0; k < 3; ++k) {
      float d0 = v[k].x - mean, d1 = v[k].y - mean;
      ssq += d0 * d0 + d1 * d1;
    }
    #pragma unroll
    for (int off = 8; off > 0; off >>= 1) ssq += __shfl_xor(ssq, off, 16);
    const float rstd = rsqrtf(ssq * (1.f / 96.f) + 1e-5f);
    float tv[6];
    float sum2 = 0.f;
    #pragma unroll
    for (int k = 0; k < 3; ++k) {
      const int c = s * 2 + k * 32;
      const float2 gg = *reinterpret_cast<const float2*>(g2 + c);
      const float2 bb = *reinterpret_cast<const float2*>(b2 + c);
      tv[2 * k]     = (v[k].x - mean) * rstd * gg.x + bb.x;
      tv[2 * k + 1] = (v[k].y - mean) * rstd * gg.y + bb.y;
      sum2 += tv[2 * k] + tv[2 * k + 1];
    }
    #pragma unroll
    for (int off = 8; off > 0; off >>= 1) sum2 += __shfl_xor(sum2, off, 16);
    const float mean2 = sum2 * (1.f / 96.f);
    float ssq2 = 0.f;
    #pragma unroll
    for (int k = 0; k < 3; ++k) {
      float d0 = tv[2 * k] - mean2, d1 = tv[2 * k + 1] - mean2;
      ssq2 += d0 * d0 + d1 * d1;
    }
    #pragma unroll
    for (int off = 8; off > 0; off >>= 1) ssq2 += __shfl_xor(ssq2, off, 16);
    const float rstd2 = rsqrtf(ssq2 * (1.f / 96.f) + 1e-5f);
    #pragma unroll
    for (int k = 0; k < 3; ++k) {
      const int c = s * 2 + k * 32;
      const float2 gg = *reinterpret_cast<const float2*>(gf + c);
      const float2 bb = *reinterpret_cast<const float2*>(bf + c);
      u16 lo = f2us((tv[2 * k]     - mean2) * rstd2 * gg.x + bb.x);
      u16 hi = f2us((tv[2 * k + 1] - mean2) * rstd2 * gg.y + bb.y);
      *reinterpret_cast<u32*>(&szb[t * 104 + c]) = (u32)lo | ((u32)hi << 16);
    }
  }
  __syncthreads();   // B1: szb complete

  const float gv = sigmoidf_(gate[0]);

  // A-frags for the single 16-row M-tile
  short8 a_pin[3];
  #pragma unroll
  for (int ks = 0; ks < 3; ++ks)
    a_pin[ks] = *reinterpret_cast<const short8*>(
        &szb[l16 * 104 + quad * 8 + ks * 32]);
  __syncthreads();   // B1b: all szb reads complete before lit (alias) writes

  // ---- pin gemm: wave w -> N-tiles [6w, 6w+6); depth-2 tile ring; softplus literals
  //      stored interleaved at cols (2o, 2o+1) as one u32 ----
  {
    short8 pb[2][3];
    #pragma unroll
    for (int p = 0; p < 2; ++p)
      #pragma unroll
      for (int ks = 0; ks < 3; ++ks)
        pb[p][ks] = *reinterpret_cast<const short8*>(
            pinwb + (size_t)((wave * 6 + p) * 16 + l16) * NC + quad * 8 + ks * 32);
    #pragma unroll
    for (int i = 0; i < 6; ++i) {
      const int o = (wave * 6 + i) * 16 + l16;      // hidden unit in [0,384)
      const float pbv = pin_b[o];
      short8 b0 = pb[i & 1][0], b1 = pb[i & 1][1], b2 = pb[i & 1][2];
      if (i + 2 < 6) {
        #pragma unroll
        for (int ks = 0; ks < 3; ++ks)
          pb[i & 1][ks] = *reinterpret_cast<const short8*>(
              pinwb + (size_t)((wave * 6 + i + 2) * 16 + l16) * NC + quad * 8 + ks * 32);
      }
      f32x4 acc = {0.f, 0.f, 0.f, 0.f};
      acc = __builtin_amdgcn_mfma_f32_16x16x32_bf16(a_pin[0], b0, acc, 0, 0, 0);
      acc = __builtin_amdgcn_mfma_f32_16x16x32_bf16(a_pin[1], b1, acc, 0, 0, 0);
      acc = __builtin_amdgcn_mfma_f32_16x16x32_bf16(a_pin[2], b2, acc, 0, 0, 0);
      #pragma unroll
      for (int r = 0; r < 4; ++r) {
        const float a0 = acc[r] + pbv;
        const float sp0 = fmaxf(a0, 0.f) + __logf(1.f + __expf(-fabsf(a0)));
        const int ta = quad * 4 + r;
        const u16 lo0 = f2us(fmaxf(a0 - sp0, LOG_EPS));
        const u16 hi0 = f2us(fmaxf(-sp0, LOG_EPS));
        *reinterpret_cast<u32*>(&lit[ta * 776 + 2 * o]) = (u32)lo0 | ((u32)hi0 << 16);
      }
    }
  }
  __syncthreads();   // B2: lit complete

  // prefetch epilogue residuals (hidden behind the clause gemm).
  // logits N-tile assignment: wave w -> tiles {w} and {w+4 if w<2}.
  const int nnt = (wave < 2) ? 2 : 1;
  int ntl[2]; ntl[0] = wave; ntl[1] = wave + 4;
  float xr[2][4];
  #pragma unroll
  for (int j = 0; j < 2; ++j) {
    if (j < nnt) {
      const int c = ntl[j] * 16 + l16;
      #pragma unroll
      for (int r = 0; r < 4; ++r)
        xr[j][r] = x1[(tok0 + quad * 4 + r) * NC + c];
    }
  }

  // ---- clause gemm: wave w -> clause tiles {2w, 2w+1}; shared A-frag; depth-4 B rings ----
  {
    const int ct0 = 2 * wave;
    const u16* bp0 = maskb + (size_t)(ct0 * 16 + l16) * NLIT + quad * 8;
    const u16* bp1 = maskb + (size_t)((ct0 + 1) * 16 + l16) * NLIT + quad * 8;
    short8 rb0[4], rb1[4];
    #pragma unroll
    for (int p = 0; p < 4; ++p) {
      rb0[p] = *reinterpret_cast<const short8*>(bp0 + p * 32);
      rb1[p] = *reinterpret_cast<const short8*>(bp1 + p * 32);
    }
    f32x4 c0 = {0.f, 0.f, 0.f, 0.f}, c1 = {0.f, 0.f, 0.f, 0.f};
    #pragma unroll
    for (int ks = 0; ks < 24; ++ks) {
      const int k0 = ks * 32 + quad * 8;
      short8 a0 = *reinterpret_cast<const short8*>(&lit[l16 * 776 + k0]);
      short8 b0 = rb0[ks & 3], b1 = rb1[ks & 3];
      if (ks + 4 < 24) {
        rb0[ks & 3] = *reinterpret_cast<const short8*>(bp0 + (ks + 4) * 32);
        rb1[ks & 3] = *reinterpret_cast<const short8*>(bp1 + (ks + 4) * 32);
      }
      c0 = __builtin_amdgcn_mfma_f32_16x16x32_bf16(a0, b0, c0, 0, 0, 0);
      c1 = __builtin_amdgcn_mfma_f32_16x16x32_bf16(a0, b1, c1, 0, 0, 0);
    }
    float e0[4], e1[4];
    #pragma unroll
    for (int r = 0; r < 4; ++r) { e0[r] = __expf(c0[r]); e1[r] = __expf(c1[r]); }
    __syncthreads();   // B2b: all lit reads complete before claT (alias) writes
    #pragma unroll
    for (int r = 0; r < 4; ++r) {
      const int ta = quad * 4 + r;
      claT[ta * 136 + ct0 * 16 + l16]        = f2us(e0[r]);
      claT[ta * 136 + (ct0 + 1) * 16 + l16]  = f2us(e1[r]);
    }
  }
  __syncthreads();   // B3: claT complete

  // ---- logits = cla @ tm_out; tiles per wave {w, w+4<2?}; fused blend epilogue ----
  #pragma unroll
  for (int j = 0; j < 2; ++j) {
    if (j < nnt) {
      const int nt = ntl[j];
      short8 btm[4];
      #pragma unroll
      for (int ks = 0; ks < 4; ++ks)
        btm[ks] = *reinterpret_cast<const short8*>(
            tmoT + (size_t)(nt * 16 + l16) * NCL_ + ks * 32 + quad * 8);
      f32x4 acc = {0.f, 0.f, 0.f, 0.f};
      #pragma unroll
      for (int ks = 0; ks < 4; ++ks) {
        const int k0 = ks * 32 + quad * 8;
        short8 a0 = *reinterpret_cast<const short8*>(&claT[l16 * 136 + k0]);
        acc = __builtin_amdgcn_mfma_f32_16x16x32_bf16(a0, btm[ks], acc, 0, 0, 0);
      }
      const int c = nt * 16 + l16;
      #pragma unroll
      for (int r = 0; r < 4; ++r) {
        const int ta = quad * 4 + r;
        float lg = acc[r];
        out[(tok0 + ta) * NC + c] = xr[j][r] + gv * lg + (1.f - gv) * sigmoidf_(lg);
      }
    }
  }
}

extern "C" void kernel_launch(void* const* d_in, const int* in_sizes, int n_in,
                              void* d_out, int out_size, void* d_ws, size_t ws_size,
                              hipStream_t stream) {
  (void)in_sizes; (void)n_in; (void)out_size; (void)ws_size;
  const float* x      = (const float*)d_in[0];
  const float* n1g    = (const float*)d_in[1];
  const float* n1b    = (const float*)d_in[2];
  const float* qkv_w  = (const float*)d_in[3];
  const float* qkv_b  = (const float*)d_in[4];
  const float* proj_w = (const float*)d_in[5];
  const float* proj_b = (const float*)d_in[6];
  const float* n2g    = (const float*)d_in[7];
  const float* n2b    = (const float*)d_in[8];
  const float* fng    = (const float*)d_in[9];
  const float* fnb    = (const float*)d_in[10];
  const float* pin_w  = (const float*)d_in[11];
  const float* pin_b  = (const float*)d_in[12];
  const float* tm_inc = (const float*)d_in[13];
  const float* tm_out = (const float*)d_in[14];
  const float* gate   = (const float*)d_in[15];

  float* x1 = (float*)d_ws;                         // NTOK*96 f32
  u16* maskb = (u16*)(x1 + (size_t)NTOK * NC);      // 128*768 bf16 (col-interleaved)
  u16* pinwb = maskb + NCL_ * NLIT;                 // 384*96 bf16
  u16* tmoT  = pinwb + HID_ * NC;                   // 96*128 bf16
  u16* qkvwb = tmoT + NC * NCL_;                    // 288*96 bf16
  u16* projwb= qkvwb + 3 * NC * NC;                 // 96*96 bf16

  hipLaunchKernelGGL(k0_prep, dim3(384), dim3(256), 0, stream,
                     tm_inc, pin_w, tm_out, qkv_w, proj_w, maskb, pinwb, tmoT, qkvwb, projwb);
  hipLaunchKernelGGL(k2_attn, dim3(NWIN), dim3(256), 0, stream,
                     x, n1g, n1b, qkvwb, qkv_b, projwb, proj_b, x1);
  hipLaunchKernelGGL(k4_ffn, dim3(NTOK / 16), dim3(256), 0, stream,
                     x1, n2g, n2b, fng, fnb, pinwb, pin_b, maskb, tmoT, gate, (float*)d_out);
}

// Round 3
// 196.540 us; speedup vs baseline: 1.1510x; 1.1510x over previous
//
#include <hip/hip_runtime.h>

// ---- problem constants (B,H0,W0,C)=(16,56,56,96), NH=3, WS=7, SS=3, HID=384, NCL=128 ----
#define NB 16
#define NHH 56
#define NWW 56
#define NC 96
#define NL (NHH*NWW)          // 3136
#define NTOK (NB*NL)          // 50176
#define WSZ 7
#define NT 49                 // tokens per window
#define SSH 3
#define NWIN 1024             // 16 * 8 * 8
#define HDIM 32
#define HID_ 384
#define NCL_ 128
#define NLIT 768
#define EPS_ 1e-6f
#define LOG_EPS -13.815510558f

typedef unsigned short u16;
typedef unsigned int   u32;
typedef __attribute__((ext_vector_type(8))) short short8;   // 8 bf16 (4 VGPRs)
typedef __attribute__((ext_vector_type(4))) float f32x4;    // MFMA C/D

__device__ __forceinline__ float us2f(u16 u) {
  union { u32 u; float f; } x; x.u = ((u32)u) << 16; return x.f;
}
__device__ __forceinline__ u16 f2us(float f) {   // RNE float->bf16
  union { float f; u32 u; } x; x.f = f;
  u32 lsb = (x.u >> 16) & 1u;
  return (u16)((x.u + 0x7fffu + lsb) >> 16);
}
__device__ __forceinline__ float sigmoidf_(float x) { return 1.f / (1.f + __expf(-x)); }

// ---------------- K0: build bf16 constants ----------------
// maskb is stored COLUMN-INTERLEAVED: permuted col q holds source literal
// j = (q&1) ? 384 + q/2 : q/2.  k4 produces literal pairs (a-sp, -sp) for
// hidden o as one u32 -> exactly cols (2o, 2o+1) of the clause A-frag.
__global__ __launch_bounds__(256) void k0_prep(const float* __restrict__ tm_inc,
                                               const float* __restrict__ pin_w,
                                               const float* __restrict__ tm_out,
                                               const float* __restrict__ qkv_w,
                                               const float* __restrict__ proj_w,
                                               u16* __restrict__ maskb,
                                               u16* __restrict__ pinwb,
                                               u16* __restrict__ tmoT,
                                               u16* __restrict__ qkvwb,
                                               u16* __restrict__ projwb) {
  int idx = blockIdx.x * 256 + threadIdx.x;
  if (idx < NCL_ * NLIT) {
    int c = idx / NLIT, q = idx - c * NLIT;
    int j = (q & 1) ? (q >> 1) + HID_ : (q >> 1);
    maskb[idx] = (tm_inc[(size_t)c * NLIT + j] > 0.f) ? (u16)0x3F80 : (u16)0;
  }
  if (idx < HID_ * NC)
    pinwb[idx] = f2us(pin_w[idx]);
  if (idx < NC * NCL_) {
    int c = idx / NCL_, k = idx - c * NCL_;
    tmoT[idx] = f2us(tm_out[(size_t)k * NC + c]);
  }
  if (idx < 3 * NC * NC)
    qkvwb[idx] = f2us(qkv_w[idx]);
  if (idx < NC * NC)
    projwb[idx] = f2us(proj_w[idx]);
}

// ---------------- K2: LN1 + window gather + MFMA attention + proj + residual scatter ----------------
// (unchanged from round 1)
__global__ __launch_bounds__(256, 4) void k2_attn(const float* __restrict__ x,
                                               const float* __restrict__ n1g,
                                               const float* __restrict__ n1b,
                                               const u16* __restrict__ qkvwb,
                                               const float* __restrict__ qkv_b,
                                               const u16* __restrict__ projwb,
                                               const float* __restrict__ proj_b,
                                               float* __restrict__ x1) {
  __shared__ __align__(16) u16 syb[64 * 104];
  __shared__ __align__(16) u16 sk [64 * 104];
  __shared__ __align__(16) u16 svT[96 * 72];
  const int tid  = threadIdx.x;
  const int wave = tid >> 6;
  const int lane = tid & 63;
  const int l16  = lane & 15;
  const int quad = lane >> 4;
  const int win  = blockIdx.x;
  const int t0   = wave * 16;
  const int bb = win >> 6, wl = win & 63;
  const int hbase = (wl >> 3) * WSZ, wbase = (wl & 7) * WSZ;

  // ---- LN1 head: 4 threads per token; gather from x with inverse global roll ----
  {
    const int t = tid >> 2, s = tid & 3;
    if (t < NT) {
      int hp = hbase + t / WSZ, wp = wbase + t % WSZ;
      int h = hp + SSH; if (h >= NHH) h -= NHH;
      int w = wp + SSH; if (w >= NWW) w -= NWW;
      const float* xp = x + ((size_t)bb * NL + (size_t)h * NWW + w) * NC;
      float4 v[6];
      float sum = 0.f;
      #pragma unroll
      for (int k = 0; k < 6; ++k) {
        v[k] = *reinterpret_cast<const float4*>(xp + s * 4 + k * 16);
        sum += v[k].x + v[k].y + v[k].z + v[k].w;
      }
      sum += __shfl_xor(sum, 1); sum += __shfl_xor(sum, 2);
      float mean = sum * (1.f / 96.f);
      float ssq = 0.f;
      #pragma unroll
      for (int k = 0; k < 6; ++k) {
        float d0 = v[k].x - mean, d1 = v[k].y - mean;
        float d2 = v[k].z - mean, d3 = v[k].w - mean;
        ssq += d0 * d0 + d1 * d1 + d2 * d2 + d3 * d3;
      }
      ssq += __shfl_xor(ssq, 1); ssq += __shfl_xor(ssq, 2);
      float rstd = rsqrtf(ssq * (1.f / 96.f) + 1e-5f);
      #pragma unroll
      for (int k = 0; k < 6; ++k) {
        int c = s * 4 + k * 16;
        const float4 g4 = *reinterpret_cast<const float4*>(n1g + c);
        const float4 b4 = *reinterpret_cast<const float4*>(n1b + c);
        syb[t * 104 + c + 0] = f2us((v[k].x - mean) * rstd * g4.x + b4.x);
        syb[t * 104 + c + 1] = f2us((v[k].y - mean) * rstd * g4.y + b4.y);
        syb[t * 104 + c + 2] = f2us((v[k].z - mean) * rstd * g4.z + b4.z);
        syb[t * 104 + c + 3] = f2us((v[k].w - mean) * rstd * g4.w + b4.w);
      }
    } else {
      #pragma unroll
      for (int k = 0; k < 6; ++k) {
        int c = s * 4 + k * 16;
        syb[t * 104 + c + 0] = 0; syb[t * 104 + c + 1] = 0;
        syb[t * 104 + c + 2] = 0; syb[t * 104 + c + 3] = 0;
      }
    }
  }
  // NO __syncthreads() here: A-frag rows below are wave-own.

  // ---- QKV: M=64, N=288 (18 tiles), K=96 (3 steps); depth-4 B-frag ring. ----
  {
    short8 afr[3];
    #pragma unroll
    for (int ks = 0; ks < 3; ++ks)
      afr[ks] = *reinterpret_cast<const short8*>(&syb[(t0 + l16) * 104 + quad * 8 + ks * 32]);
    short8 rb[4][3];
    #pragma unroll
    for (int p = 0; p < 4; ++p)
      #pragma unroll
      for (int ks = 0; ks < 3; ++ks)
        rb[p][ks] = *reinterpret_cast<const short8*>(
            qkvwb + (size_t)(p * 16 + l16) * NC + quad * 8 + ks * 32);
    #pragma unroll
    for (int nt = 0; nt < 18; ++nt) {
      const int n0 = nt * 16;
      const float bias = qkv_b[n0 + l16];
      short8 b0 = rb[nt & 3][0], b1 = rb[nt & 3][1], b2 = rb[nt & 3][2];
      if (nt + 4 < 18) {
        #pragma unroll
        for (int ks = 0; ks < 3; ++ks)
          rb[nt & 3][ks] = *reinterpret_cast<const short8*>(
              qkvwb + (size_t)((nt + 4) * 16 + l16) * NC + quad * 8 + ks * 32);
      }
      f32x4 acc = {0.f, 0.f, 0.f, 0.f};
      acc = __builtin_amdgcn_mfma_f32_16x16x32_bf16(afr[0], b0, acc, 0, 0, 0);
      acc = __builtin_amdgcn_mfma_f32_16x16x32_bf16(afr[1], b1, acc, 0, 0, 0);
      acc = __builtin_amdgcn_mfma_f32_16x16x32_bf16(afr[2], b2, acc, 0, 0, 0);
      const int part = nt / 6;                 // 0=q 1=k 2=v
      const int oc = n0 - part * 96 + l16;
      if (part < 2) {
        u16* dst = (part == 0) ? syb : sk;     // q overwrites y in wave-own rows
        #pragma unroll
        for (int r = 0; r < 4; ++r)
          dst[(t0 + quad * 4 + r) * 104 + oc] = f2us(acc[r] + bias);
      } else {
        #pragma unroll
        for (int r = 0; r < 4; ++r)
          svT[oc * 72 + (t0 + quad * 4 + r)] = f2us(acc[r] + bias);
      }
    }
  }
  __syncthreads();   // B2: k/v (cross-wave) must be complete

  // ---- all-head scores first, then per-head softmax+PV ----
  u16* spw = sk + wave * 16 * 72;              // sp ALIASES sk (sk dead after score phase)
  const float sscale = 0.17677669529663687f;
  short8 qf[3];
  f32x4 s[3][4];
  #pragma unroll
  for (int h = 0; h < 3; ++h)
    qf[h] = *reinterpret_cast<const short8*>(&syb[(t0 + l16) * 104 + h * HDIM + quad * 8]);
  #pragma unroll
  for (int h = 0; h < 3; ++h) {
    const int d0 = h * HDIM;
    #pragma unroll
    for (int nt = 0; nt < 4; ++nt) {
      short8 kf = *reinterpret_cast<const short8*>(&sk[(nt * 16 + l16) * 104 + d0 + quad * 8]);
      f32x4 a = {0.f, 0.f, 0.f, 0.f};
      s[h][nt] = __builtin_amdgcn_mfma_f32_16x16x32_bf16(qf[h], kf, a, 0, 0, 0);
    }
  }
  __syncthreads();   // B3s: all sk reads complete before spw (sk-alias) writes
  #pragma unroll
  for (int h = 0; h < 3; ++h) {
    const int d0 = h * HDIM;
    #pragma unroll
    for (int nt = 0; nt < 4; ++nt)
      #pragma unroll
      for (int r = 0; r < 4; ++r) s[h][nt][r] *= sscale;
    if (l16 >= 1) {                       // key col 48+l16 >= 49 -> mask
      #pragma unroll
      for (int r = 0; r < 4; ++r) s[h][3][r] = -1e30f;
    }
    #pragma unroll
    for (int r = 0; r < 4; ++r) {
      float m = fmaxf(fmaxf(s[h][0][r], s[h][1][r]), fmaxf(s[h][2][r], s[h][3][r]));
      #pragma unroll
      for (int off = 8; off > 0; off >>= 1) m = fmaxf(m, __shfl_xor(m, off, 16));
      float e0 = __expf(s[h][0][r] - m), e1 = __expf(s[h][1][r] - m);
      float e2 = __expf(s[h][2][r] - m), e3 = __expf(s[h][3][r] - m);
      float sum = e0 + e1 + e2 + e3;
      #pragma unroll
      for (int off = 8; off > 0; off >>= 1) sum += __shfl_xor(sum, off, 16);
      float inv = 1.f / sum;
      const int row = quad * 4 + r;
      spw[row * 72 +      l16] = f2us(e0 * inv);
      spw[row * 72 + 16 + l16] = f2us(e1 * inv);
      spw[row * 72 + 32 + l16] = f2us(e2 * inv);
      spw[row * 72 + 48 + l16] = f2us(e3 * inv);
    }
    short8 pa[2];
    pa[0] = *reinterpret_cast<const short8*>(&spw[l16 * 72 + quad * 8]);
    pa[1] = *reinterpret_cast<const short8*>(&spw[l16 * 72 + 32 + quad * 8]);
    #pragma unroll
    for (int nt = 0; nt < 2; ++nt) {
      const int c0 = d0 + nt * 16;
      f32x4 acc = {0.f, 0.f, 0.f, 0.f};
      #pragma unroll
      for (int ks = 0; ks < 2; ++ks) {
        short8 vb = *reinterpret_cast<const short8*>(&svT[(c0 + l16) * 72 + ks * 32 + quad * 8]);
        acc = __builtin_amdgcn_mfma_f32_16x16x32_bf16(pa[ks], vb, acc, 0, 0, 0);
      }
      #pragma unroll
      for (int r = 0; r < 4; ++r)
        syb[(t0 + quad * 4 + r) * 104 + c0 + l16] = f2us(acc[r]);
    }
  }

  // ---- proj: N=96 (6 tiles), K=96 (3 steps); prefetched residuals + depth-2 B ring ----
  {
    short8 aa[3];
    #pragma unroll
    for (int ks = 0; ks < 3; ++ks)
      aa[ks] = *reinterpret_cast<const short8*>(&syb[(t0 + l16) * 104 + quad * 8 + ks * 32]);

    size_t tokr[4]; bool tval[4];
    #pragma unroll
    for (int r = 0; r < 4; ++r) {
      const int t = t0 + quad * 4 + r;
      tval[r] = (t < NT);
      int rr = t / WSZ + SSH; if (rr >= WSZ) rr -= WSZ;
      int qq = t % WSZ + SSH; if (qq >= WSZ) qq -= WSZ;
      tokr[r] = (size_t)bb * NL + (size_t)(hbase + rr) * NWW + (wbase + qq);
    }
    float xv[6][4];
    #pragma unroll
    for (int nt = 0; nt < 6; ++nt)
      #pragma unroll
      for (int r = 0; r < 4; ++r)
        xv[nt][r] = tval[r] ? x[tokr[r] * NC + nt * 16 + l16] : 0.f;

    short8 pbr[2][3];
    #pragma unroll
    for (int ks = 0; ks < 3; ++ks)
      pbr[0][ks] = *reinterpret_cast<const short8*>(
          projwb + (size_t)l16 * NC + quad * 8 + ks * 32);
    #pragma unroll
    for (int nt = 0; nt < 6; ++nt) {
      const int n0 = nt * 16;
      const float pb = proj_b[n0 + l16];
      short8 b0 = pbr[nt & 1][0], b1 = pbr[nt & 1][1], b2 = pbr[nt & 1][2];
      if (nt + 1 < 6) {
        #pragma unroll
        for (int ks = 0; ks < 3; ++ks)
          pbr[(nt + 1) & 1][ks] = *reinterpret_cast<const short8*>(
              projwb + (size_t)((nt + 1) * 16 + l16) * NC + quad * 8 + ks * 32);
      }
      f32x4 acc = {0.f, 0.f, 0.f, 0.f};
      acc = __builtin_amdgcn_mfma_f32_16x16x32_bf16(aa[0], b0, acc, 0, 0, 0);
      acc = __builtin_amdgcn_mfma_f32_16x16x32_bf16(aa[1], b1, acc, 0, 0, 0);
      acc = __builtin_amdgcn_mfma_f32_16x16x32_bf16(aa[2], b2, acc, 0, 0, 0);
      #pragma unroll
      for (int r = 0; r < 4; ++r) {
        if (tval[r])
          x1[tokr[r] * NC + n0 + l16] = xv[nt][r] + acc[r] + pb;
      }
    }
  }
}

// ---- K4 helper: literal pair pack (softplus, bf16, interleaved cols) ----
__device__ __forceinline__ short8 lit_pack(f32x4 p, f32x4 pbv) {
  union { short8 s; u32 w[4]; } u;
  #pragma unroll
  for (int r = 0; r < 4; ++r) {
    const float a  = p[r] + pbv[r];
    const float sp = fmaxf(a, 0.f) + __logf(1.f + __expf(-fabsf(a)));
    const u16 lo = f2us(fmaxf(a - sp, LOG_EPS));
    const u16 hi = f2us(fmaxf(-sp,    LOG_EPS));
    u.w[r] = (u32)lo | ((u32)hi << 16);
  }
  return u.s;
}

// ---- K4 fused step: pin tile ks (swapped mfma) -> softplus -> clause MFMAs.
// Swapped pin gemm: A = pinwb rows (hidden), B = z tokens. C col=l16=token,
// row=quad*4+r=hidden-within-tile -> lit_pack output IS the clause A-frag u32[r]
// for this very lane (cols ks*32+quad*8, token l16). Zero shuffles, zero LDS.
__device__ __forceinline__ void k4_step(int ks, bool pref,
    const u16* __restrict__ pinwb, const float* __restrict__ pin_b,
    const u16* __restrict__ maskb, int l16, int quad,
    short8 (&pa)[3], f32x4& pbv, short8 (&mb)[8],
    const short8 (&zb)[2][3], f32x4 (&cacc)[2][8]) {
  const short8 a0 = pa[0], a1 = pa[1], a2 = pa[2];
  const f32x4 pb = pbv;
  f32x4 p0 = {0.f, 0.f, 0.f, 0.f}, p1 = {0.f, 0.f, 0.f, 0.f};
  p0 = __builtin_amdgcn_mfma_f32_16x16x32_bf16(a0, zb[0][0], p0, 0, 0, 0);
  p1 = __builtin_amdgcn_mfma_f32_16x16x32_bf16(a0, zb[1][0], p1, 0, 0, 0);
  p0 = __builtin_amdgcn_mfma_f32_16x16x32_bf16(a1, zb[0][1], p0, 0, 0, 0);
  p1 = __builtin_amdgcn_mfma_f32_16x16x32_bf16(a1, zb[1][1], p1, 0, 0, 0);
  p0 = __builtin_amdgcn_mfma_f32_16x16x32_bf16(a2, zb[0][2], p0, 0, 0, 0);
  p1 = __builtin_amdgcn_mfma_f32_16x16x32_bf16(a2, zb[1][2], p1, 0, 0, 0);
  if (pref) {   // ping-pong prefetch for tile ks+2 (this buffer's next use)
    const u16* pp = pinwb + (size_t)((ks + 2) * 16 + l16) * NC + quad * 8;
    pa[0] = *reinterpret_cast<const short8*>(pp);
    pa[1] = *reinterpret_cast<const short8*>(pp + 32);
    pa[2] = *reinterpret_cast<const short8*>(pp + 64);
    pbv   = *reinterpret_cast<const f32x4*>(pin_b + (ks + 2) * 16 + quad * 4);
  }
  const short8 lf0 = lit_pack(p0, pb);
  const short8 lf1 = lit_pack(p1, pb);
  #pragma unroll
  for (int ct = 0; ct < 8; ++ct) {
    cacc[0][ct] = __builtin_amdgcn_mfma_f32_16x16x32_bf16(lf0, mb[ct], cacc[0][ct], 0, 0, 0);
    cacc[1][ct] = __builtin_amdgcn_mfma_f32_16x16x32_bf16(lf1, mb[ct], cacc[1][ct], 0, 0, 0);
  }
  if (pref) {
    #pragma unroll
    for (int ct = 0; ct < 8; ++ct)
      mb[ct] = *reinterpret_cast<const short8*>(
          maskb + (size_t)(ct * 16 + l16) * NLIT + (ks + 2) * 32 + quad * 8);
  }
}

__device__ __forceinline__ float sum4_(float4 v) { return (v.x + v.y) + (v.z + v.w); }

// ---------------- K4: fused register-resident TM-FFN; 128 tokens/block, 4 waves, NO barriers ----------------
// Each wave independently owns 32 tokens (2 MFMA token-groups): double-LN (in-register,
// quad-butterfly reduce) -> zb B-frags -> fused loop over 24 hidden tiles
// {swapped pin MFMA -> softplus/pack -> 16 clause MFMAs} -> exp -> wave-private
// claT (LDS, no barrier: same-wave RAW via lgkmcnt) -> logits MFMA -> blend epilogue.
// LDS = 4 waves * 32*136*2 = 34,816 B. No __syncthreads anywhere.
__global__ __launch_bounds__(256, 2) void k4_ffn(const float* __restrict__ x1,
                                              const float* __restrict__ g2,
                                              const float* __restrict__ b2,
                                              const float* __restrict__ gf,
                                              const float* __restrict__ bf,
                                              const u16* __restrict__ pinwb,
                                              const float* __restrict__ pin_b,
                                              const u16* __restrict__ maskb,
                                              const u16* __restrict__ tmoT,
                                              const float* __restrict__ gate,
                                              float* __restrict__ out) {
  __shared__ __align__(16) u16 claT_s[4 * 32 * 136];
  const int tid  = threadIdx.x;
  const int wave = tid >> 6;
  const int lane = tid & 63;
  const int l16  = lane & 15;
  const int quad = lane >> 4;
  u16* claT = claT_s + wave * 32 * 136;
  const size_t tok0 = (size_t)blockIdx.x * 128 + wave * 32;

  // ---- double-LN directly into zb B-frags ----
  // lane (l16,quad) owns token tok0+g*16+l16, channels {k*32+quad*8 .. +7}, k=0..2.
  // 96-ch reduction = 2-step shfl_xor(16,32) butterfly across the 4 quads.
  float4 g2v[3][2], b2v[3][2], gfv[3][2], bfv[3][2];
  #pragma unroll
  for (int k = 0; k < 3; ++k) {
    const int c = k * 32 + quad * 8;
    g2v[k][0] = *reinterpret_cast<const float4*>(g2 + c);
    g2v[k][1] = *reinterpret_cast<const float4*>(g2 + c + 4);
    b2v[k][0] = *reinterpret_cast<const float4*>(b2 + c);
    b2v[k][1] = *reinterpret_cast<const float4*>(b2 + c + 4);
    gfv[k][0] = *reinterpret_cast<const float4*>(gf + c);
    gfv[k][1] = *reinterpret_cast<const float4*>(gf + c + 4);
    bfv[k][0] = *reinterpret_cast<const float4*>(bf + c);
    bfv[k][1] = *reinterpret_cast<const float4*>(bf + c + 4);
  }
  short8 zb[2][3];
  #pragma unroll
  for (int g = 0; g < 2; ++g) {
    const float* xp = x1 + (tok0 + g * 16 + l16) * NC + quad * 8;
    float4 va[3], vb[3];
    float sum = 0.f;
    #pragma unroll
    for (int k = 0; k < 3; ++k) {
      va[k] = *reinterpret_cast<const float4*>(xp + k * 32);
      vb[k] = *reinterpret_cast<const float4*>(xp + k * 32 + 4);
      sum += sum4_(va[k]) + sum4_(vb[k]);
    }
    sum += __shfl_xor(sum, 16); sum += __shfl_xor(sum, 32);
    const float mean = sum * (1.f / 96.f);
    float ssq = 0.f;
    #pragma unroll
    for (int k = 0; k < 3; ++k) {
      float d;
      d = va[k].x - mean; ssq += d * d;  d = va[k].y - mean; ssq += d * d;
      d = va[k].z - mean; ssq += d * d;  d = va[k].w - mean; ssq += d * d;
      d = vb[k].x - mean; ssq += d * d;  d = vb[k].y - mean; ssq += d * d;
      d = vb[k].z - mean; ssq += d * d;  d = vb[k].w - mean; ssq += d * d;
    }
    ssq += __shfl_xor(ssq, 16); ssq += __shfl_xor(ssq, 32);
    const float rstd = rsqrtf(ssq * (1.f / 96.f) + 1e-5f);
    float sum2 = 0.f;
    #pragma unroll
    for (int k = 0; k < 3; ++k) {
      va[k].x = (va[k].x - mean) * rstd * g2v[k][0].x + b2v[k][0].x; sum2 += va[k].x;
      va[k].y = (va[k].y - mean) * rstd * g2v[k][0].y + b2v[k][0].y; sum2 += va[k].y;
      va[k].z = (va[k].z - mean) * rstd * g2v[k][0].z + b2v[k][0].z; sum2 += va[k].z;
      va[k].w = (va[k].w - mean) * rstd * g2v[k][0].w + b2v[k][0].w; sum2 += va[k].w;
      vb[k].x = (vb[k].x - mean) * rstd * g2v[k][1].x + b2v[k][1].x; sum2 += vb[k].x;
      vb[k].y = (vb[k].y - mean) * rstd * g2v[k][1].y + b2v[k][1].y; sum2 += vb[k].y;
      vb[k].z = (vb[k].z - mean) * rstd * g2v[k][1].z + b2v[k][1].z; sum2 += vb[k].z;
      vb[k].w = (vb[k].w - mean) * rstd * g2v[k][1].w + b2v[k][1].w; sum2 += vb[k].w;
    }
    sum2 += __shfl_xor(sum2, 16); sum2 += __shfl_xor(sum2, 32);
    const float mean2 = sum2 * (1.f / 96.f);
    float ssq2 = 0.f;
    #pragma unroll
    for (int k = 0; k < 3; ++k) {
      float d;
      d = va[k].x - mean2; ssq2 += d * d;  d = va[k].y - mean2; ssq2 += d * d;
      d = va[k].z - mean2; ssq2 += d * d;  d = va[k].w - mean2; ssq2 += d * d;
      d = vb[k].x - mean2; ssq2 += d * d;  d = vb[k].y - mean2; ssq2 += d * d;
      d = vb[k].z - mean2; ssq2 += d * d;  d = vb[k].w - mean2; ssq2 += d * d;
    }
    ssq2 += __shfl_xor(ssq2, 16); ssq2 += __shfl_xor(ssq2, 32);
    const float rstd2 = rsqrtf(ssq2 * (1.f / 96.f) + 1e-5f);
    #pragma unroll
    for (int k = 0; k < 3; ++k) {
      const float z0 = (va[k].x - mean2) * rstd2 * gfv[k][0].x + bfv[k][0].x;
      const float z1 = (va[k].y - mean2) * rstd2 * gfv[k][0].y + bfv[k][0].y;
      const float z2 = (va[k].z - mean2) * rstd2 * gfv[k][0].z + bfv[k][0].z;
      const float z3 = (va[k].w - mean2) * rstd2 * gfv[k][0].w + bfv[k][0].w;
      const float z4 = (vb[k].x - mean2) * rstd2 * gfv[k][1].x + bfv[k][1].x;
      const float z5 = (vb[k].y - mean2) * rstd2 * gfv[k][1].y + bfv[k][1].y;
      const float z6 = (vb[k].z - mean2) * rstd2 * gfv[k][1].z + bfv[k][1].z;
      const float z7 = (vb[k].w - mean2) * rstd2 * gfv[k][1].w + bfv[k][1].w;
      union { short8 s; u32 w[4]; } uz;
      uz.w[0] = (u32)f2us(z0) | ((u32)f2us(z1) << 16);
      uz.w[1] = (u32)f2us(z2) | ((u32)f2us(z3) << 16);
      uz.w[2] = (u32)f2us(z4) | ((u32)f2us(z5) << 16);
      uz.w[3] = (u32)f2us(z6) | ((u32)f2us(z7) << 16);
      zb[g][k] = uz.s;
    }
  }

  // ---- prologue: load pin tiles 0/1, bias vectors, maskb slices ks=0/1 ----
  short8 paA[3], paB[3], mbA[8], mbB[8];
  f32x4 pbvA, pbvB;
  {
    const u16* pp0 = pinwb + (size_t)(l16) * NC + quad * 8;
    const u16* pp1 = pinwb + (size_t)(16 + l16) * NC + quad * 8;
    #pragma unroll
    for (int k = 0; k < 3; ++k) {
      paA[k] = *reinterpret_cast<const short8*>(pp0 + k * 32);
      paB[k] = *reinterpret_cast<const short8*>(pp1 + k * 32);
    }
    pbvA = *reinterpret_cast<const f32x4*>(pin_b + quad * 4);
    pbvB = *reinterpret_cast<const f32x4*>(pin_b + 16 + quad * 4);
    #pragma unroll
    for (int ct = 0; ct < 8; ++ct) {
      const u16* mp = maskb + (size_t)(ct * 16 + l16) * NLIT + quad * 8;
      mbA[ct] = *reinterpret_cast<const short8*>(mp);
      mbB[ct] = *reinterpret_cast<const short8*>(mp + 32);
    }
  }
  f32x4 cacc[2][8];
  {
    const f32x4 z4 = {0.f, 0.f, 0.f, 0.f};
    #pragma unroll
    for (int g = 0; g < 2; ++g)
      #pragma unroll
      for (int ct = 0; ct < 8; ++ct)
        cacc[g][ct] = z4;
  }

  // ---- fused pin->softplus->clause loop over 24 hidden tiles (rolled; ping-pong rings) ----
  for (int kk = 0; kk < 12; ++kk) {
    k4_step(2 * kk,     kk < 11, pinwb, pin_b, maskb, l16, quad, paA, pbvA, mbA, zb, cacc);
    k4_step(2 * kk + 1, kk < 11, pinwb, pin_b, maskb, l16, quad, paB, pbvB, mbB, zb, cacc);
  }

  // ---- residual prefetch (overlaps claT staging + logits loads) ----
  float xr[2][6][4];
  #pragma unroll
  for (int g = 0; g < 2; ++g)
    #pragma unroll
    for (int nt = 0; nt < 6; ++nt)
      #pragma unroll
      for (int r = 0; r < 4; ++r)
        xr[g][nt][r] = x1[(tok0 + g * 16 + quad * 4 + r) * NC + nt * 16 + l16];

  // ---- clauses = exp(cacc) -> wave-private claT (same-wave RAW, no barrier) ----
  #pragma unroll
  for (int g = 0; g < 2; ++g)
    #pragma unroll
    for (int ct = 0; ct < 8; ++ct)
      #pragma unroll
      for (int r = 0; r < 4; ++r)
        claT[(g * 16 + quad * 4 + r) * 136 + ct * 16 + l16] = f2us(__expf(cacc[g][ct][r]));

  // ---- logits = cla @ tm_out + fused blend epilogue ----
  short8 caf[2][4];
  #pragma unroll
  for (int g = 0; g < 2; ++g)
    #pragma unroll
    for (int ks = 0; ks < 4; ++ks)
      caf[g][ks] = *reinterpret_cast<const short8*>(
          &claT[(g * 16 + l16) * 136 + ks * 32 + quad * 8]);
  const float gv = sigmoidf_(gate[0]);
  #pragma unroll
  for (int nt = 0; nt < 6; ++nt) {
    short8 btm[4];
    #pragma unroll
    for (int ks = 0; ks < 4; ++ks)
      btm[ks] = *reinterpret_cast<const short8*>(
          tmoT + (size_t)(nt * 16 + l16) * NCL_ + ks * 32 + quad * 8);
    f32x4 o0 = {0.f, 0.f, 0.f, 0.f}, o1 = {0.f, 0.f, 0.f, 0.f};
    #pragma unroll
    for (int ks = 0; ks < 4; ++ks) {
      o0 = __builtin_amdgcn_mfma_f32_16x16x32_bf16(caf[0][ks], btm[ks], o0, 0, 0, 0);
      o1 = __builtin_amdgcn_mfma_f32_16x16x32_bf16(caf[1][ks], btm[ks], o1, 0, 0, 0);
    }
    const int c = nt * 16 + l16;
    #pragma unroll
    for (int r = 0; r < 4; ++r) {
      const float lg0 = o0[r], lg1 = o1[r];
      out[(tok0 + quad * 4 + r) * NC + c]      = xr[0][nt][r] + gv * lg0 + (1.f - gv) * sigmoidf_(lg0);
      out[(tok0 + 16 + quad * 4 + r) * NC + c] = xr[1][nt][r] + gv * lg1 + (1.f - gv) * sigmoidf_(lg1);
    }
  }
}

extern "C" void kernel_launch(void* const* d_in, const int* in_sizes, int n_in,
                              void* d_out, int out_size, void* d_ws, size_t ws_size,
                              hipStream_t stream) {
  (void)in_sizes; (void)n_in; (void)out_size; (void)ws_size;
  const float* x      = (const float*)d_in[0];
  const float* n1g    = (const float*)d_in[1];
  const float* n1b    = (const float*)d_in[2];
  const float* qkv_w  = (const float*)d_in[3];
  const float* qkv_b  = (const float*)d_in[4];
  const float* proj_w = (const float*)d_in[5];
  const float* proj_b = (const float*)d_in[6];
  const float* n2g    = (const float*)d_in[7];
  const float* n2b    = (const float*)d_in[8];
  const float* fng    = (const float*)d_in[9];
  const float* fnb    = (const float*)d_in[10];
  const float* pin_w  = (const float*)d_in[11];
  const float* pin_b  = (const float*)d_in[12];
  const float* tm_inc = (const float*)d_in[13];
  const float* tm_out = (const float*)d_in[14];
  const float* gate   = (const float*)d_in[15];

  float* x1 = (float*)d_ws;                         // NTOK*96 f32
  u16* maskb = (u16*)(x1 + (size_t)NTOK * NC);      // 128*768 bf16 (col-interleaved)
  u16* pinwb = maskb + NCL_ * NLIT;                 // 384*96 bf16
  u16* tmoT  = pinwb + HID_ * NC;                   // 96*128 bf16
  u16* qkvwb = tmoT + NC * NCL_;                    // 288*96 bf16
  u16* projwb= qkvwb + 3 * NC * NC;                 // 96*96 bf16

  hipLaunchKernelGGL(k0_prep, dim3(384), dim3(256), 0, stream,
                     tm_inc, pin_w, tm_out, qkv_w, proj_w, maskb, pinwb, tmoT, qkvwb, projwb);
  hipLaunchKernelGGL(k2_attn, dim3(NWIN), dim3(256), 0, stream,
                     x, n1g, n1b, qkvwb, qkv_b, projwb, proj_b, x1);
  hipLaunchKernelGGL(k4_ffn, dim3(NTOK / 128), dim3(256), 0, stream,
                     x1, n2g, n2b, fng, fnb, pinwb, pin_b, maskb, tmoT, gate, (float*)d_out);
}